// Round 1
// 1396.120 us; speedup vs baseline: 1.0007x; 1.0007x over previous
//
#include <hip/hip_runtime.h>

#define IMG 512
#define CCH 128
#define NHEAD 4
#define NTOK 64
#define SHIFT_AMT 4

typedef __attribute__((ext_vector_type(8))) short bf16x8;
typedef __attribute__((ext_vector_type(4))) float f32x4;
typedef __attribute__((ext_vector_type(4))) unsigned int u32x4;
typedef __attribute__((ext_vector_type(2))) unsigned int u32x2;

union BF8 { u32x4 u; bf16x8 b; };

__device__ __forceinline__ unsigned cvtpk(float lo, float hi) {
    unsigned r;
    asm("v_cvt_pk_bf16_f32 %0, %1, %2" : "=v"(r) : "v"(lo), "v"(hi));
    return r;
}

__device__ __forceinline__ short f2bf(float f) {
    unsigned u = __float_as_uint(f);
    unsigned r = (u + 0x7FFFu + ((u >> 16) & 1u)) >> 16;
    return (short)r;
}

// ---------------- pre-kernel: transpose+convert weights, precompute bias[4][64][64] ----------------
// ws layout: [0)       wqkvt bf16 [384][128]
//            [98304 B) wpt   bf16 [128][128]
//            [131072B) biasM f32  [4][key 64][q 64]
__global__ __launch_bounds__(256)
void cvt_weights(const float* __restrict__ qkv_w, const float* __restrict__ proj_w,
                 const float* __restrict__ bias_table,
                 short* __restrict__ wqkvt, short* __restrict__ wpt, float* __restrict__ biasM)
{
    int idx = blockIdx.x * 256 + threadIdx.x;   // 0 .. 81919
    if (idx < 384 * 128) {
        int n = idx >> 7, k = idx & 127;
        wqkvt[idx] = f2bf(qkv_w[k * 384 + n]);
    } else if (idx < 384 * 128 + 128 * 128) {
        int i2 = idx - 384 * 128;
        int n = i2 >> 7, k = i2 & 127;
        wpt[i2] = f2bf(proj_w[k * 128 + n]);
    } else {
        int i3 = idx - (384 * 128 + 128 * 128);          // h*4096 + key*64 + q
        int h = i3 >> 12, key = (i3 >> 6) & 63, q = i3 & 63;
        int rel = ((q >> 3) - (key >> 3) + 7) * 15 + ((q & 7) - (key & 7) + 7);
        biasM[i3] = bias_table[rel * NHEAD + h];
    }
}

// ---------------- main kernel: one block (256 thr, 4 waves) per 8x8 window ----------------
// LDS 49152 B -> 3 blocks/CU. Single barrier; LDS read-only afterwards.
__global__ __launch_bounds__(256, 3)
void win_attn_mfma(const float* __restrict__ x,
                   const short* __restrict__ wqkvt,
                   const float* __restrict__ qkv_b,
                   const short* __restrict__ wpt,
                   const float* __restrict__ proj_b,
                   const float* __restrict__ biasM,
                   float* __restrict__ out)
{
    // XOR-swizzled, unpadded tiles (swizzle: elem ^= (row&7)<<3, i.e. 16B-chunk ^ row&7)
    __shared__ __align__(16) short qs[NTOK * CCH];   // [tok][ch]
    __shared__ __align__(16) short ks[NTOK * CCH];   // [tok][ch]
    __shared__ __align__(16) short vt[CCH * NTOK];   // [ch][tok]

    const int tid  = threadIdx.x;
    const int wv   = tid >> 6;
    const int lane = tid & 63;
    const int l16  = lane & 15;
    const int q16  = lane >> 4;

    const int widx = blockIdx.x;
    const int b  = widx >> 12;
    const int wh = (widx >> 6) & 63;
    const int ww = widx & 63;

    const f32x4 zf = {0.f, 0.f, 0.f, 0.f};

    // ---------------- Phase 1: QKV GEMM. wave wv owns output channels [96wv, 96wv+96) ----------------
    unsigned xoff[4];
    #pragma unroll
    for (int mt = 0; mt < 4; ++mt) {
        const int tok = mt * 16 + l16;
        const int hh_ = (wh * 8 + (tok >> 3) + SHIFT_AMT) & (IMG - 1);
        const int ww_ = (ww * 8 + (tok & 7)  + SHIFT_AMT) & (IMG - 1);
        xoff[mt] = (((unsigned)b * IMG + hh_) * IMG + ww_) * CCH;
    }

    f32x4 acc1[6][4];                      // bias folded into C-init
    #pragma unroll
    for (int nt = 0; nt < 6; ++nt) {
        const float bv = qkv_b[wv * 96 + nt * 16 + l16];
        #pragma unroll
        for (int mt = 0; mt < 4; ++mt) acc1[nt][mt] = (f32x4){bv, bv, bv, bv};
    }

    #pragma unroll
    for (int kk = 0; kk < 4; ++kk) {
        bf16x8 a[4];
        #pragma unroll
        for (int mt = 0; mt < 4; ++mt) {
            const float* p = x + xoff[mt] + kk * 32 + q16 * 8;
            const float4 f0 = *(const float4*)p;
            const float4 f1 = *(const float4*)(p + 4);
            BF8 cv;
            cv.u = (u32x4){cvtpk(f0.x, f0.y), cvtpk(f0.z, f0.w),
                           cvtpk(f1.x, f1.y), cvtpk(f1.z, f1.w)};
            a[mt] = cv.b;
        }
        #pragma unroll
        for (int nt = 0; nt < 6; ++nt) {
            const bf16x8 bw = *(const bf16x8*)(wqkvt + (wv * 96 + nt * 16 + l16) * 128 + kk * 32 + q16 * 8);
            #pragma unroll
            for (int mt = 0; mt < 4; ++mt)
                acc1[nt][mt] = __builtin_amdgcn_mfma_f32_16x16x32_bf16(a[mt], bw, acc1[nt][mt], 0, 0, 0);
        }
    }

    // epilogue: pack to bf16 (cvt_pk), swizzled LDS writes
    #pragma unroll
    for (int nt = 0; nt < 6; ++nt) {
        const int n0  = wv * 96 + nt * 16;
        const int col = n0 + l16;
        #pragma unroll
        for (int mt = 0; mt < 4; ++mt) {
            const unsigned p01 = cvtpk(acc1[nt][mt][0], acc1[nt][mt][1]);
            const unsigned p23 = cvtpk(acc1[nt][mt][2], acc1[nt][mt][3]);
            const int t0 = mt * 16 + q16 * 4;
            if (n0 < 128) {
                qs[(t0+0)*CCH + (col ^ (((t0+0)&7)<<3))] = (short)(p01 & 0xFFFFu);
                qs[(t0+1)*CCH + (col ^ (((t0+1)&7)<<3))] = (short)(p01 >> 16);
                qs[(t0+2)*CCH + (col ^ (((t0+2)&7)<<3))] = (short)(p23 & 0xFFFFu);
                qs[(t0+3)*CCH + (col ^ (((t0+3)&7)<<3))] = (short)(p23 >> 16);
            } else if (n0 < 256) {
                const int kc = col - 128;
                ks[(t0+0)*CCH + (kc ^ (((t0+0)&7)<<3))] = (short)(p01 & 0xFFFFu);
                ks[(t0+1)*CCH + (kc ^ (((t0+1)&7)<<3))] = (short)(p01 >> 16);
                ks[(t0+2)*CCH + (kc ^ (((t0+2)&7)<<3))] = (short)(p23 & 0xFFFFu);
                ks[(t0+3)*CCH + (kc ^ (((t0+3)&7)<<3))] = (short)(p23 >> 16);
            } else {
                const int ch = col - 256;
                u32x2 pk2 = {p01, p23};
                *(u32x2*)&vt[ch * NTOK + (t0 ^ ((ch & 7) << 3))] = pk2;
            }
        }
    }
    __syncthreads();     // ONLY barrier; LDS is read-only from here on

    // ---------------- Phase 2: attention, swapped (S^T = K Q^T). wave wv owns queries [16wv,16wv+16) ----------------
    // lane (l16,q16): s[nt][r] = S^T[key = nt*16+q16*4+r][q = wv*16+l16]
    const int myA = l16 + ((lane & 16) << 1);    // src lane of quad 2*(q16&1)
    const int myB = myA + 16;                    // quad 2*(q16&1)+1
    const bool hiq = (lane >= 32);               // q16>>1
    const int qrow = wv * 16 + l16;
    const float scale = 0.17677669529663687f;    // 1/sqrt(32)
    const float* bM = biasM + q16 * 256 + qrow;  // + h*4096 + nt*1024 + r*64

    unsigned ok[16];                             // packed O^T bf16: [h][ntv][rr]

    #pragma unroll
    for (int h = 0; h < NHEAD; ++h) {
        const bf16x8 bq = *(const bf16x8*)&qs[qrow * CCH + ((h*32 + q16*8) ^ ((qrow & 7) << 3))];
        f32x4 s[4];
        #pragma unroll
        for (int nt = 0; nt < 4; ++nt) {
            const int krow = nt * 16 + l16;
            const bf16x8 ak = *(const bf16x8*)&ks[krow * CCH + ((h*32 + q16*8) ^ ((krow & 7) << 3))];
            s[nt] = __builtin_amdgcn_mfma_f32_16x16x32_bf16(ak, bq, zf, 0, 0, 0);
        }
        // scale + bias, then in-register softmax over keys (15 reg ops + 2 shuffles)
        float mx = -3.0e38f;
        #pragma unroll
        for (int nt = 0; nt < 4; ++nt)
            #pragma unroll
            for (int r = 0; r < 4; ++r) {
                s[nt][r] = s[nt][r] * scale + bM[h*4096 + nt*1024 + r*64];
                mx = fmaxf(mx, s[nt][r]);
            }
        mx = fmaxf(mx, __shfl_xor(mx, 16));
        mx = fmaxf(mx, __shfl_xor(mx, 32));
        float sum = 0.f;
        #pragma unroll
        for (int nt = 0; nt < 4; ++nt)
            #pragma unroll
            for (int r = 0; r < 4; ++r) {
                s[nt][r] = __expf(s[nt][r] - mx);
                sum += s[nt][r];
            }
        sum += __shfl_xor(sum, 16);
        sum += __shfl_xor(sum, 32);
        const float inv = 1.f / sum;             // deferred: applied to O, not P

        // pack P~ (unnormalized, <=1) to bf16 pairs: pkf[nt*2+rr] = keys nt*16+q16*4+{2rr,2rr+1}
        unsigned pkf[8];
        #pragma unroll
        for (int nt = 0; nt < 4; ++nt) {
            pkf[nt*2+0] = cvtpk(s[nt][0], s[nt][1]);
            pkf[nt*2+1] = cvtpk(s[nt][2], s[nt][3]);
        }

        // O^T = V^T * P^T.  B-frag slot m of kk needs keys kk*32+q16*8+2m+{0,1}:
        //   src lane quad = 2*(q16&1)+(m>>1), src reg = 4kk + 2*(q16>>1) + (m&1)  (l16 preserved)
        f32x4 o0 = zf, o1 = zf;
        #pragma unroll
        for (int kk = 0; kk < 2; ++kk) {
            const unsigned a0 = __shfl(pkf[4*kk+0], myA), b0 = __shfl(pkf[4*kk+2], myA);
            const unsigned a1 = __shfl(pkf[4*kk+1], myA), b1 = __shfl(pkf[4*kk+3], myA);
            const unsigned a2 = __shfl(pkf[4*kk+0], myB), b2 = __shfl(pkf[4*kk+2], myB);
            const unsigned a3 = __shfl(pkf[4*kk+1], myB), b3 = __shfl(pkf[4*kk+3], myB);
            BF8 bp;
            bp.u = (u32x4){hiq ? b0 : a0, hiq ? b1 : a1, hiq ? b2 : a2, hiq ? b3 : a3};
            const int c0 = h * 32 + l16;
            const int c1 = c0 + 16;
            const bf16x8 av0 = *(const bf16x8*)&vt[c0 * NTOK + ((kk*32 + q16*8) ^ ((c0 & 7) << 3))];
            const bf16x8 av1 = *(const bf16x8*)&vt[c1 * NTOK + ((kk*32 + q16*8) ^ ((c1 & 7) << 3))];
            o0 = __builtin_amdgcn_mfma_f32_16x16x32_bf16(av0, bp.b, o0, 0, 0, 0);
            o1 = __builtin_amdgcn_mfma_f32_16x16x32_bf16(av1, bp.b, o1, 0, 0, 0);
        }
        // apply deferred 1/sum, pack O^T: ch = h*32+ntv*16+q16*4+{2rr,2rr+1}, col q = wv*16+l16
        ok[h*4+0] = cvtpk(o0[0]*inv, o0[1]*inv);
        ok[h*4+1] = cvtpk(o0[2]*inv, o0[3]*inv);
        ok[h*4+2] = cvtpk(o1[0]*inv, o1[1]*inv);
        ok[h*4+3] = cvtpk(o1[2]*inv, o1[3]*inv);
    }

    // ---------------- Phase 3: projection, fully wave-independent (no LDS) ----------------
    // A-frag slot m of kk needs ch = kk*32+q16*8+2m+{0,1}: same gather pattern as P
    f32x4 c2[8];
    #pragma unroll
    for (int nt = 0; nt < 8; ++nt) {
        const float pb = proj_b[nt * 16 + l16];
        c2[nt] = (f32x4){pb, pb, pb, pb};
    }

    #pragma unroll
    for (int kk = 0; kk < 4; ++kk) {
        const unsigned a0 = __shfl(ok[4*kk+0], myA), b0 = __shfl(ok[4*kk+2], myA);
        const unsigned a1 = __shfl(ok[4*kk+1], myA), b1 = __shfl(ok[4*kk+3], myA);
        const unsigned a2 = __shfl(ok[4*kk+0], myB), b2 = __shfl(ok[4*kk+2], myB);
        const unsigned a3 = __shfl(ok[4*kk+1], myB), b3 = __shfl(ok[4*kk+3], myB);
        BF8 am;
        am.u = (u32x4){hiq ? b0 : a0, hiq ? b1 : a1, hiq ? b2 : a2, hiq ? b3 : a3};
        #pragma unroll
        for (int nt = 0; nt < 8; ++nt) {
            const bf16x8 bw = *(const bf16x8*)(wpt + (nt * 16 + l16) * 128 + kk * 32 + q16 * 8);
            c2[nt] = __builtin_amdgcn_mfma_f32_16x16x32_bf16(am.b, bw, c2[nt], 0, 0, 0);
        }
    }

    // store: token = wv*16 + q16*4 + r -> hh_ lane-constant, ww_ = base + r
    const int hh_ = (wh * 8 + 2 * wv + (q16 >> 1) + SHIFT_AMT) & (IMG - 1);
    const unsigned wbase = ww * 8 + 4 * (q16 & 1) + SHIFT_AMT;
    #pragma unroll
    for (int r = 0; r < 4; ++r) {
        const int ww_ = (wbase + r) & (IMG - 1);
        float* po = out + (((unsigned)b * IMG + hh_) * IMG + ww_) * CCH + l16;
        #pragma unroll
        for (int nt = 0; nt < 8; ++nt) po[nt * 16] = c2[nt][r];
    }
}

extern "C" void kernel_launch(void* const* d_in, const int* in_sizes, int n_in,
                              void* d_out, int out_size, void* d_ws, size_t ws_size,
                              hipStream_t stream)
{
    const float* x        = (const float*)d_in[0];
    const float* qkv_w    = (const float*)d_in[1];
    const float* qkv_b    = (const float*)d_in[2];
    const float* proj_w   = (const float*)d_in[3];
    const float* proj_b   = (const float*)d_in[4];
    const float* bias_tab = (const float*)d_in[5];
    float* out = (float*)d_out;

    short* wqkvt = (short*)d_ws;                     // 384*128 bf16
    short* wpt   = wqkvt + 384 * 128;                // 128*128 bf16
    float* biasM = (float*)((char*)d_ws + 131072);   // 4*64*64 f32 (65536 B)

    hipLaunchKernelGGL(cvt_weights, dim3(320), dim3(256), 0, stream,
                       qkv_w, proj_w, bias_tab, wqkvt, wpt, biasM);
    hipLaunchKernelGGL(win_attn_mfma, dim3(4 * 64 * 64), dim3(256), 0, stream,
                       x, wqkvt, qkv_b, wpt, proj_b, biasM, out);
}